// Round 8
// baseline (119.524 us; speedup 1.0000x reference)
//
#include <hip/hip_runtime.h>

#define VOL   65536
#define NSC   12
#define DIAG  4.1f
#define SPB   16                  // sites per block = one x-line
#define THREADS 192               // 3 waves; wave w owns rows 4w..4w+3 of all 16 sites
#define KWF   1536                // floats per wave K phase-buffer: 2(re,im) x 16 sites x 48
#define PSI_LINE 192              // floats per x-line per (re|im)
#define NXCD  8

#define CMADD(kr, ki, vr, vi)                                              \
    sr += kr.x * vr.x - ki.x * vi.x;  si += kr.x * vi.x + ki.x * vr.x;     \
    sr += kr.y * vr.y - ki.y * vi.y;  si += kr.y * vi.y + ki.y * vr.y;     \
    sr += kr.z * vr.z - ki.z * vi.z;  si += kr.z * vi.z + ki.z * vr.z;     \
    sr += kr.w * vr.w - ki.w * vi.w;  si += kr.w * vi.w + ki.w * vr.w;

__device__ __forceinline__ void g2lds16(const float* g, float* l) {
    __builtin_amdgcn_global_load_lds(
        (const __attribute__((address_space(1))) unsigned int*)g,
        (__attribute__((address_space(3))) unsigned int*)l,
        16, 0, 0);
}

#define WAITV(n) asm volatile("s_waitcnt vmcnt(" #n ")" ::: "memory")
#define WAITL()  asm volatile("s_waitcnt lgkmcnt(0)" ::: "memory")
#define SBAR()   __builtin_amdgcn_sched_barrier(0)

// Stage this wave's row-group (rows 4w..4w+3) of 16 sites for phase P into kwb.
template<int P>
__device__ __forceinline__ void stageK(const float* __restrict__ Kf_re,
                                       const float* __restrict__ Kf_im,
                                       const float* __restrict__ Kb_re,
                                       const float* __restrict__ Kb_im,
                                       int site0, int w, int l,
                                       const int* goff, float* kwb) {
    constexpr int mu = P >> 1;
    const float* re = (P & 1) ? Kb_re : Kf_re;
    const float* im = (P & 1) ? Kb_im : Kf_im;
    const size_t gb = ((size_t)(mu * VOL) + (size_t)site0) * 36 + (size_t)w * 12;
    #pragma unroll
    for (int jj = 0; jj < 3; ++jj) {
        const size_t g4 = gb + (size_t)goff[jj];   // goff = s*36 + f for c=jj*64+l
        g2lds16(re + 4 * g4, kwb + 0 * 768 + jj * 256 + l * 4);
        g2lds16(im + 4 * g4, kwb + 1 * 768 + jj * 256 + l * 4);
    }
}

// Pure-LDS compute for phase P: lane (s = l>>2, r = l&3) does the complex
// row-dot of K row (4w+r) with the neighbor psi vector of site s.
// psi layout (linear): pbuf[(line*2+ar)*PSI_LINE + site*12 + f]
template<int P>
__device__ __forceinline__ void phase_compute(const float* __restrict__ kwb,
                                              const float* __restrict__ pbuf,
                                              int s, int r,
                                              float& acc_re, float& acc_im) {
    constexpr int mu = P >> 1;
    constexpr int d  = P & 1;                       // 0 = fwd(+1), 1 = bwd(-1)
    constexpr int line = (mu < 3) ? (1 + mu * 2 + d) : 0;
    const int sidx = (mu < 3) ? s : (d == 0 ? (s + 1) & 15 : (s + 15) & 15);

    const float4* k4 = (const float4*)kwb;
    const int kb = s * 12 + r * 3;                  // float4 idx of this lane's row
    const float4* vr = (const float4*)(pbuf + (line * 2 + 0) * PSI_LINE + sidx * 12);
    const float4* vi = (const float4*)(pbuf + (line * 2 + 1) * PSI_LINE + sidx * 12);

    float sr = 0.f, si = 0.f;
    #pragma unroll
    for (int q = 0; q < 3; ++q) {
        const float4 a = k4[kb + q];                // K re
        const float4 b = k4[192 + kb + q];          // K im
        const float4 x = vr[q];                     // psi re
        const float4 y4 = vi[q];                    // psi im
        CMADD(a, b, x, y4);
    }
    acc_re -= 0.5f * sr;
    acc_im -= 0.5f * si;
}

__global__ __launch_bounds__(THREADS) void dslash_kernel(
    const float* __restrict__ psi_re, const float* __restrict__ psi_im,
    const float* __restrict__ Kf_re,  const float* __restrict__ Kf_im,
    const float* __restrict__ Kb_re,  const float* __restrict__ Kb_im,
    float* __restrict__ out_re,       float* __restrict__ out_im)
{
    __shared__ float kbuf[3][2][KWF];          // 36.9 KB per-wave double-buffered K
    __shared__ float pbuf[7 * 2 * PSI_LINE];   // 10.5 KB psi, linear layout

    const int j  = threadIdx.x;
    const int w  = j >> 6;              // wave 0..2 -> rows 4w..4w+3
    const int l  = j & 63;
    const int s  = l >> 2;              // site 0..15
    const int r  = l & 3;               // row within row-group

    // T1: XCD-aware chunked swizzle. 4096 blocks % 8 == 0 -> bijective.
    // XCD k gets contiguous block range [k*512, (k+1)*512): y,z (and mostly t)
    // neighbor lines land on the same XCD's L2 -> psi re-reads become L2 hits.
    const int lid = (blockIdx.x % NXCD) * (VOL / SPB / NXCD) + blockIdx.x / NXCD;

    const int site0 = lid * SPB;
    const int y = lid & 15, z = (lid >> 4) & 15, t = (lid >> 8) & 15;

    // per-lane staging map: slot c = jj*64+l  ->  (site = c/12, f = c%12)
    int goff[3];
    #pragma unroll
    for (int jj = 0; jj < 3; ++jj) {
        const int c = jj * 64 + l;
        const int ss = c / 12;
        goff[jj] = ss * 36 + (c - ss * 12);
    }

    // global float base of each psi x-line (192 floats per line per re|im)
    int lb[7];
    lb[0] = lid * 192;
    lb[1] = ((((t + 1)  & 15) << 8) | (z << 4) | y) * 192;   // t+
    lb[2] = ((((t + 15) & 15) << 8) | (z << 4) | y) * 192;   // t-
    lb[3] = ((t << 8) | (((z + 1)  & 15) << 4) | y) * 192;   // z+
    lb[4] = ((t << 8) | (((z + 15) & 15) << 4) | y) * 192;   // z-
    lb[5] = ((t << 8) | (z << 4) | ((y + 1)  & 15)) * 192;   // y+
    lb[6] = ((t << 8) | (z << 4) | ((y + 15) & 15)) * 192;   // y-

    // ---- psi prologue: linear copy, contiguous float4 per lane ----
    #pragma unroll
    for (int rr = 0; rr < 4; ++rr) {
        const int idx = j + rr * THREADS;          // need 672 = 7*2*48
        if (idx < 672) {
            const int c  = idx % 48;               // float4 within (line,ar)
            const int la = idx / 48;
            const int ar = la & 1, ln = la >> 1;
            const float4 v = *(const float4*)((ar ? psi_im : psi_re) + lb[ln] + c * 4);
            *(float4*)&pbuf[(ln * 2 + ar) * PSI_LINE + c * 4] = v;
        }
    }
    SBAR();   // keep stage issues strictly after psi loads/writes (clean vmcnt ledger)

    float* kwb0 = &kbuf[w][0][0];
    float* kwb1 = &kbuf[w][1][0];
    stageK<0>(Kf_re, Kf_im, Kb_re, Kb_im, site0, w, l, goff, kwb0);
    stageK<1>(Kf_re, Kf_im, Kb_re, Kb_im, site0, w, l, goff, kwb1);
    SBAR();
    WAITL();                               // psi ds_writes done
    __builtin_amdgcn_s_barrier();          // the ONLY barrier: pbuf ready

    // diag term: lane owns element (site s, row 4w+r)
    float acc_re = DIAG * pbuf[0 * PSI_LINE + s * 12 + 4 * w + r];
    float acc_im = DIAG * pbuf[1 * PSI_LINE + s * 12 + 4 * w + r];

    // ---- 8 phases, barrier-free, per-wave counted vmcnt ----
#define PHASE(P, NW)                                                          \
    WAITV(NW);                                                                \
    SBAR();                                                                   \
    phase_compute<P>(((P) & 1) ? kwb1 : kwb0, pbuf, s, r, acc_re, acc_im);    \
    WAITL();   /* own ds_reads drained before DMA overwrite of this buffer */ \
    SBAR();

    PHASE(0, 6) stageK<2>(Kf_re, Kf_im, Kb_re, Kb_im, site0, w, l, goff, kwb0);
    PHASE(1, 6) stageK<3>(Kf_re, Kf_im, Kb_re, Kb_im, site0, w, l, goff, kwb1);
    PHASE(2, 6) stageK<4>(Kf_re, Kf_im, Kb_re, Kb_im, site0, w, l, goff, kwb0);
    PHASE(3, 6) stageK<5>(Kf_re, Kf_im, Kb_re, Kb_im, site0, w, l, goff, kwb1);
    PHASE(4, 6) stageK<6>(Kf_re, Kf_im, Kb_re, Kb_im, site0, w, l, goff, kwb0);
    PHASE(5, 6) stageK<7>(Kf_re, Kf_im, Kb_re, Kb_im, site0, w, l, goff, kwb1);
    PHASE(6, 6)
    PHASE(7, 0)

    // lane holds output element (site0+s, row 4w+r)
    const int o = (site0 + s) * NSC + 4 * w + r;
    out_re[o] = acc_re;
    out_im[o] = acc_im;
}

extern "C" void kernel_launch(void* const* d_in, const int* in_sizes, int n_in,
                              void* d_out, int out_size, void* d_ws, size_t ws_size,
                              hipStream_t stream) {
    const float* psi_re = (const float*)d_in[0];
    const float* psi_im = (const float*)d_in[1];
    const float* Kf_re  = (const float*)d_in[2];
    const float* Kf_im  = (const float*)d_in[3];
    const float* Kb_re  = (const float*)d_in[4];
    const float* Kb_im  = (const float*)d_in[5];

    float* out_re = (float*)d_out;
    float* out_im = (float*)d_out + (size_t)VOL * NSC;

    dslash_kernel<<<VOL / SPB, THREADS, 0, stream>>>(psi_re, psi_im,
                                                     Kf_re, Kf_im, Kb_re, Kb_im,
                                                     out_re, out_im);
}

// Round 9
// 113.078 us; speedup vs baseline: 1.0570x; 1.0570x over previous
//
#include <hip/hip_runtime.h>

#define VOL   65536
#define NSC   12
#define DIAG  4.1f
#define SPB   16                  // sites per block = one x-line
#define THREADS 192               // 3 waves; wave w owns rows 4w..4w+3 of all 16 sites
#define KWF   1536                // floats per wave K phase-buffer: 2(re,im) x 16 sites x 48
#define PSI_LINE 192              // floats per x-line per (re|im)

#define CMADD(kr, ki, vr, vi)                                              \
    sr += kr.x * vr.x - ki.x * vi.x;  si += kr.x * vi.x + ki.x * vr.x;     \
    sr += kr.y * vr.y - ki.y * vi.y;  si += kr.y * vi.y + ki.y * vr.y;     \
    sr += kr.z * vr.z - ki.z * vi.z;  si += kr.z * vi.z + ki.z * vr.z;     \
    sr += kr.w * vr.w - ki.w * vi.w;  si += kr.w * vi.w + ki.w * vr.w;

__device__ __forceinline__ void g2lds16(const float* g, float* l) {
    __builtin_amdgcn_global_load_lds(
        (const __attribute__((address_space(1))) unsigned int*)g,
        (__attribute__((address_space(3))) unsigned int*)l,
        16, 0, 0);
}

#define WAITV(n) asm volatile("s_waitcnt vmcnt(" #n ")" ::: "memory")
#define WAITL()  asm volatile("s_waitcnt lgkmcnt(0)" ::: "memory")
#define SBAR()   __builtin_amdgcn_sched_barrier(0)

// Stage this wave's row-group (rows 4w..4w+3) of 16 sites for phase P into kwb.
template<int P>
__device__ __forceinline__ void stageK(const float* __restrict__ Kf_re,
                                       const float* __restrict__ Kf_im,
                                       const float* __restrict__ Kb_re,
                                       const float* __restrict__ Kb_im,
                                       int site0, int w, int l,
                                       const int* goff, float* kwb) {
    constexpr int mu = P >> 1;
    const float* re = (P & 1) ? Kb_re : Kf_re;
    const float* im = (P & 1) ? Kb_im : Kf_im;
    const size_t gb = ((size_t)(mu * VOL) + (size_t)site0) * 36 + (size_t)w * 12;
    #pragma unroll
    for (int jj = 0; jj < 3; ++jj) {
        const size_t g4 = gb + (size_t)goff[jj];   // goff = s*36 + f for c=jj*64+l
        g2lds16(re + 4 * g4, kwb + 0 * 768 + jj * 256 + l * 4);
        g2lds16(im + 4 * g4, kwb + 1 * 768 + jj * 256 + l * 4);
    }
}

// Pure-LDS compute for phase P: lane (s = l>>2, r = l&3) does the complex
// row-dot of K row (4w+r) with the neighbor psi vector of site s.
// psi layout (linear): pbuf[(line*2+ar)*PSI_LINE + site*12 + f]
template<int P>
__device__ __forceinline__ void phase_compute(const float* __restrict__ kwb,
                                              const float* __restrict__ pbuf,
                                              int s, int r,
                                              float& acc_re, float& acc_im) {
    constexpr int mu = P >> 1;
    constexpr int d  = P & 1;                       // 0 = fwd(+1), 1 = bwd(-1)
    constexpr int line = (mu < 3) ? (1 + mu * 2 + d) : 0;
    const int sidx = (mu < 3) ? s : (d == 0 ? (s + 1) & 15 : (s + 15) & 15);

    const float4* k4 = (const float4*)kwb;
    const int kb = s * 12 + r * 3;                  // float4 idx of this lane's row
    const float4* vr = (const float4*)(pbuf + (line * 2 + 0) * PSI_LINE + sidx * 12);
    const float4* vi = (const float4*)(pbuf + (line * 2 + 1) * PSI_LINE + sidx * 12);

    float sr = 0.f, si = 0.f;
    #pragma unroll
    for (int q = 0; q < 3; ++q) {
        const float4 a = k4[kb + q];                // K re
        const float4 b = k4[192 + kb + q];          // K im
        const float4 x = vr[q];                     // psi re
        const float4 y4 = vi[q];                    // psi im
        CMADD(a, b, x, y4);
    }
    acc_re -= 0.5f * sr;
    acc_im -= 0.5f * si;
}

__global__ __launch_bounds__(THREADS) void dslash_kernel(
    const float* __restrict__ psi_re, const float* __restrict__ psi_im,
    const float* __restrict__ Kf_re,  const float* __restrict__ Kf_im,
    const float* __restrict__ Kb_re,  const float* __restrict__ Kb_im,
    float* __restrict__ out_re,       float* __restrict__ out_im)
{
    __shared__ float kbuf[3][2][KWF];          // 36.9 KB per-wave double-buffered K
    __shared__ float pbuf[7 * 2 * PSI_LINE];   // 10.5 KB psi, linear layout

    const int j  = threadIdx.x;
    const int w  = j >> 6;              // wave 0..2 -> rows 4w..4w+3
    const int l  = j & 63;
    const int s  = l >> 2;              // site 0..15
    const int r  = l & 3;               // row within row-group
    const int lid = blockIdx.x;         // (t*16+z)*16+y  (default mapping — swizzle hurt)
    const int site0 = lid * SPB;
    const int y = lid & 15, z = (lid >> 4) & 15, t = (lid >> 8) & 15;

    // per-lane staging map: slot c = jj*64+l  ->  (site = c/12, f = c%12)
    int goff[3];
    #pragma unroll
    for (int jj = 0; jj < 3; ++jj) {
        const int c = jj * 64 + l;
        const int ss = c / 12;
        goff[jj] = ss * 36 + (c - ss * 12);
    }

    // global float base of each psi x-line (192 floats per line per re|im)
    int lb[7];
    lb[0] = lid * 192;
    lb[1] = ((((t + 1)  & 15) << 8) | (z << 4) | y) * 192;   // t+
    lb[2] = ((((t + 15) & 15) << 8) | (z << 4) | y) * 192;   // t-
    lb[3] = ((t << 8) | (((z + 1)  & 15) << 4) | y) * 192;   // z+
    lb[4] = ((t << 8) | (((z + 15) & 15) << 4) | y) * 192;   // z-
    lb[5] = ((t << 8) | (z << 4) | ((y + 1)  & 15)) * 192;   // y+
    lb[6] = ((t << 8) | (z << 4) | ((y + 15) & 15)) * 192;   // y-

    // ---- psi prologue: linear copy, contiguous float4 per lane ----
    #pragma unroll
    for (int rr = 0; rr < 4; ++rr) {
        const int idx = j + rr * THREADS;          // need 672 = 7*2*48
        if (idx < 672) {
            const int c  = idx % 48;               // float4 within (line,ar)
            const int la = idx / 48;
            const int ar = la & 1, ln = la >> 1;
            const float4 v = *(const float4*)((ar ? psi_im : psi_re) + lb[ln] + c * 4);
            *(float4*)&pbuf[(ln * 2 + ar) * PSI_LINE + c * 4] = v;
        }
    }
    SBAR();   // keep stage issues strictly after psi loads/writes (clean vmcnt ledger)

    float* kwb0 = &kbuf[w][0][0];
    float* kwb1 = &kbuf[w][1][0];
    stageK<0>(Kf_re, Kf_im, Kb_re, Kb_im, site0, w, l, goff, kwb0);
    stageK<1>(Kf_re, Kf_im, Kb_re, Kb_im, site0, w, l, goff, kwb1);
    SBAR();
    WAITL();                               // psi ds_writes done
    __builtin_amdgcn_s_barrier();          // the ONLY barrier: pbuf ready

    // diag term: lane owns element (site s, row 4w+r)
    float acc_re = DIAG * pbuf[0 * PSI_LINE + s * 12 + 4 * w + r];
    float acc_im = DIAG * pbuf[1 * PSI_LINE + s * 12 + 4 * w + r];

    // ---- 8 phases, barrier-free, per-wave counted vmcnt ----
#define PHASE(P, NW)                                                          \
    WAITV(NW);                                                                \
    SBAR();                                                                   \
    phase_compute<P>(((P) & 1) ? kwb1 : kwb0, pbuf, s, r, acc_re, acc_im);    \
    WAITL();   /* own ds_reads drained before DMA overwrite of this buffer */ \
    SBAR();

    PHASE(0, 6) stageK<2>(Kf_re, Kf_im, Kb_re, Kb_im, site0, w, l, goff, kwb0);
    PHASE(1, 6) stageK<3>(Kf_re, Kf_im, Kb_re, Kb_im, site0, w, l, goff, kwb1);
    PHASE(2, 6) stageK<4>(Kf_re, Kf_im, Kb_re, Kb_im, site0, w, l, goff, kwb0);
    PHASE(3, 6) stageK<5>(Kf_re, Kf_im, Kb_re, Kb_im, site0, w, l, goff, kwb1);
    PHASE(4, 6) stageK<6>(Kf_re, Kf_im, Kb_re, Kb_im, site0, w, l, goff, kwb0);
    PHASE(5, 6) stageK<7>(Kf_re, Kf_im, Kb_re, Kb_im, site0, w, l, goff, kwb1);
    PHASE(6, 6)
    PHASE(7, 0)

    // lane holds output element (site0+s, row 4w+r)
    const int o = (site0 + s) * NSC + 4 * w + r;
    out_re[o] = acc_re;
    out_im[o] = acc_im;
}

extern "C" void kernel_launch(void* const* d_in, const int* in_sizes, int n_in,
                              void* d_out, int out_size, void* d_ws, size_t ws_size,
                              hipStream_t stream) {
    const float* psi_re = (const float*)d_in[0];
    const float* psi_im = (const float*)d_in[1];
    const float* Kf_re  = (const float*)d_in[2];
    const float* Kf_im  = (const float*)d_in[3];
    const float* Kb_re  = (const float*)d_in[4];
    const float* Kb_im  = (const float*)d_in[5];

    float* out_re = (float*)d_out;
    float* out_im = (float*)d_out + (size_t)VOL * NSC;

    dslash_kernel<<<VOL / SPB, THREADS, 0, stream>>>(psi_re, psi_im,
                                                     Kf_re, Kf_im, Kb_re, Kb_im,
                                                     out_re, out_im);
}